// Round 11
// baseline (4141.736 us; speedup 1.0000x reference)
//
#include <hip/hip_runtime.h>
#include <stdint.h>

#define SS 64
#define BB 64
#define TT 100
#define HOPC 256
#define NFC 256
#define GCC 256
#define ICC 512
#define NC (1.0f/127.0f)
#define NBLK 64       // one block per chain
#define NTHR 512      // 8 waves
#define SKW_STRIDE 328    // padded LDS row stride (halves) for skip_dense

// f16 weight arena offsets (in halves; same order as inputs 6..19)
#define OFF_FW     0
#define OFF_FWGLU  8192
#define OFF_G1IH   12288
#define OFF_G1HH   36864
#define OFF_GLU1   49152
#define OFF_G2IH   53248
#define OFF_G2HH   77824
#define OFF_GLU2   90112
#define OFF_G3IH   94208
#define OFF_G3HH   118784
#define OFF_GLU3   131072
#define OFF_SKIPD  135168
#define OFF_SKIPG  176128
#define OFF_OUT    192512
#define W_TOTAL    200704
#define XALL_F32   (TT * BB * HOPC)   // 1,638,400 floats
#define UG_FLOATS  ((size_t)400 * 64 * 704)   // 72.1 MB

typedef _Float16 f16;
typedef _Float16 h2 __attribute__((ext_vector_type(2)));
typedef _Float16 f16x4v __attribute__((ext_vector_type(4)));
typedef _Float16 f16x8v __attribute__((ext_vector_type(8)));
typedef float f32x4v __attribute__((ext_vector_type(4)));
union U16 { uint4 u; h2 h[4]; };

#if __has_builtin(__builtin_amdgcn_fdot2)
#define FDOT2(a, b, c) __builtin_amdgcn_fdot2((a), (b), (c), false)
#else
#define FDOT2(a, b, c) ((c) + (float)(a)[0] * (float)(b)[0] + (float)(a)[1] * (float)(b)[1])
#endif

#define MFMA16(a, b, c) __builtin_amdgcn_mfma_f32_16x16x32_f16((a), (b), (c), 0, 0, 0)

// ---------------- threefry2x32 core ----------------
__device__ __forceinline__ uint32_t rotl32(uint32_t x, int r) {
    return (x << r) | (x >> (32 - r));
}

__device__ __forceinline__ void tf2x32(uint32_t k0, uint32_t k1, uint32_t c0, uint32_t c1,
                                       uint32_t& o0, uint32_t& o1) {
    uint32_t k2 = k0 ^ k1 ^ 0x1BD11BDAu;
    uint32_t x0 = c0 + k0, x1 = c1 + k1;
    x0 += x1; x1 = rotl32(x1, 13); x1 ^= x0;
    x0 += x1; x1 = rotl32(x1, 15); x1 ^= x0;
    x0 += x1; x1 = rotl32(x1, 26); x1 ^= x0;
    x0 += x1; x1 = rotl32(x1, 6);  x1 ^= x0;
    x0 += k1; x1 += k2 + 1u;
    x0 += x1; x1 = rotl32(x1, 17); x1 ^= x0;
    x0 += x1; x1 = rotl32(x1, 29); x1 ^= x0;
    x0 += x1; x1 = rotl32(x1, 16); x1 ^= x0;
    x0 += x1; x1 = rotl32(x1, 24); x1 ^= x0;
    x0 += k2; x1 += k0 + 2u;
    x0 += x1; x1 = rotl32(x1, 13); x1 ^= x0;
    x0 += x1; x1 = rotl32(x1, 15); x1 ^= x0;
    x0 += x1; x1 = rotl32(x1, 26); x1 ^= x0;
    x0 += x1; x1 = rotl32(x1, 6);  x1 ^= x0;
    x0 += k0; x1 += k1 + 3u;
    x0 += x1; x1 = rotl32(x1, 17); x1 ^= x0;
    x0 += x1; x1 = rotl32(x1, 29); x1 ^= x0;
    x0 += x1; x1 = rotl32(x1, 16); x1 ^= x0;
    x0 += x1; x1 = rotl32(x1, 24); x1 ^= x0;
    x0 += k1; x1 += k2 + 4u;
    x0 += x1; x1 = rotl32(x1, 13); x1 ^= x0;
    x0 += x1; x1 = rotl32(x1, 15); x1 ^= x0;
    x0 += x1; x1 = rotl32(x1, 26); x1 ^= x0;
    x0 += x1; x1 = rotl32(x1, 6);  x1 ^= x0;
    x0 += k2; x1 += k0 + 5u;
    o0 = x0; o1 = x1;
}

__device__ __forceinline__ float unifP(uint32_t k0, uint32_t k1, uint32_t m) {
    uint32_t o0, o1;
    tf2x32(k0, k1, 0u, m, o0, o1);
    uint32_t bits = o0 ^ o1;
    return __uint_as_float((bits >> 9) | 0x3f800000u) - 1.0f;
}

__device__ __forceinline__ float clipf(float v) { return fminf(1.0f, fmaxf(-1.0f, v)); }
__device__ __forceinline__ float noiseu(float v, float u) {
    return clipf(v + (u - 0.5f) * NC);
}
__device__ __forceinline__ float sigmf(float v) {
    return __fdividef(1.0f, 1.0f + __expf(-v));
}
__device__ __forceinline__ float tanhfast(float x) {
    float ax = fminf(fabsf(x), 15.0f);
    float e = __expf(2.0f * ax);
    float r = __fdividef(e - 1.0f, e + 1.0f);
    return copysignf(r, x);
}

// barrier WITHOUT the vmcnt(0) drain __syncthreads() would emit.
__device__ __forceinline__ void bar_lds() {
    asm volatile("s_waitcnt lgkmcnt(0)\n\ts_barrier" ::: "memory");
}

// ---------------- DPP 8-lane reduction (fallback kernel) --------------------
__device__ __forceinline__ float red8dpp(float v) {
    int t;
    t = __builtin_amdgcn_update_dpp(0, __float_as_int(v), 0xB1, 0xF, 0xF, true);
    v += __int_as_float(t);
    t = __builtin_amdgcn_update_dpp(0, __float_as_int(v), 0x4E, 0xF, 0xF, true);
    v += __int_as_float(t);
    t = __builtin_amdgcn_update_dpp(0, __float_as_int(v), 0x141, 0xF, 0xF, true);
    v += __int_as_float(t);
    return v;
}

__device__ __forceinline__ float dotU(const U16& w, const U16& x, float acc) {
#pragma unroll
    for (int i = 0; i < 4; ++i) acc = FDOT2(w.h[i], x.h[i], acc);
    return acc;
}

// ---------------- MFMA helpers ----------------
// A-fragment: lane l supplies row (rowbase + l&15), k = kc*32 + (l>>4)*8 + j.
// B-fragment broadcast: every lane loads x[(l>>4)*8 + j] -> all 16 cols equal,
// so every lane's C regs hold y[(l>>4)*4 + reg] (C/D layout: col=l&15,
// row=(l>>4)*4+reg, verified learn_hip m89). Same k-order for A and B => the
// HW slot pairing makes the dot product correct.
__device__ __forceinline__ f16x8v ldfragG(const f16* W, int K, int rowbase, int kc, int l) {
    return *(const f16x8v*)(W + (size_t)(rowbase + (l & 15)) * K + kc * 32 + ((l >> 4) << 3));
}
__device__ __forceinline__ f16x8v ldbL(const f16* base, int l) {
    return *(const f16x8v*)(base + ((l >> 4) << 3));
}
// select element r (0..3) from f32x4 with runtime r -- constant extracts +
// cndmask selects, no dynamic vector indexing (stays in registers).
__device__ __forceinline__ float sel4(f32x4v v, int r) {
    float a = (r & 1) ? v[1] : v[0];
    float b = (r & 1) ? v[3] : v[2];
    return (r & 2) ? b : a;
}

// ---------------- register weight structs (fallback kernel) ----------------
struct WF1  { U16 w[2]; };
struct WGRU { U16 wih[6]; U16 whh[3]; U16 glu; };
struct WSK  { U16 w[10]; };
struct WSG  { U16 w[4]; };

__device__ __forceinline__ void ldF1(const f16* W, int row, int g, WF1& r) {
    const f16* p = W + row * 128 + g * 16;
    r.w[0].u = *(const uint4*)p;
    r.w[1].u = *(const uint4*)(p + 8);
}
__device__ __forceinline__ void ldF2(const f16* W, int row, int g, U16& r) {
    r.u = *(const uint4*)(W + row * 64 + g * 8);
}
__device__ __forceinline__ void ldGRU(const f16* Wih, const f16* Whh, const f16* Glu,
                                      int row, int g, WGRU& r) {
#pragma unroll
    for (int j = 0; j < 3; ++j) {
        const f16* p = Wih + (row + 64 * j) * 128 + g * 16;
        r.wih[2 * j].u     = *(const uint4*)p;
        r.wih[2 * j + 1].u = *(const uint4*)(p + 8);
        r.whh[j].u = *(const uint4*)(Whh + (row + 64 * j) * 64 + g * 8);
    }
    r.glu.u = *(const uint4*)(Glu + row * 64 + g * 8);
}
__device__ __forceinline__ void ldSK(const f16* W, int row, int g, WSK& r) {
#pragma unroll
    for (int j = 0; j < 2; ++j) {
        const f16* p = W + (row + 64 * j) * 320 + g * 40;
#pragma unroll
        for (int i = 0; i < 5; ++i) r.w[5 * j + i].u = *(const uint4*)(p + 8 * i);
    }
}
__device__ __forceinline__ void ldSG(const f16* W, int row, int g, WSG& r) {
#pragma unroll
    for (int j = 0; j < 2; ++j) {
        const f16* p = W + (row + 64 * j) * 128 + g * 16;
        r.w[2 * j].u     = *(const uint4*)p;
        r.w[2 * j + 1].u = *(const uint4*)(p + 8);
    }
}
__device__ __forceinline__ void pinU(U16& r) {
    asm volatile("" : "+v"(r.u.x), "+v"(r.u.y), "+v"(r.u.z), "+v"(r.u.w));
}

// ---------------- weight convert to f16 ----------------
struct SrcW { const float* p[14]; };

__global__ __launch_bounds__(256) void fargan_cvtw(SrcW s, f16* __restrict__ dst) {
    const int offs[15] = {0, 8192, 12288, 36864, 49152, 53248, 77824, 90112,
                          94208, 118784, 131072, 135168, 176128, 192512, 200704};
    int i = blockIdx.x * 256 + threadIdx.x;
    if (i >= W_TOTAL) return;
    int sgi = 0;
#pragma unroll
    for (int t = 1; t < 14; ++t) sgi += (i >= offs[t]);
    dst[i] = (f16)s.p[sgi][i - offs[sgi]];
}

// ---------------- feature transpose ----------------
__global__ __launch_bounds__(256) void fargan_tr(const float* __restrict__ f,
                                                 float* __restrict__ fT) {
    __shared__ float L[64][104];
    int b = blockIdx.x >> 2, c0 = (blockIdx.x & 3) * 64;
    for (int e = threadIdx.x; e < 6400; e += 256) {
        int r = e / 100, col = e - r * 100;
        L[r][col] = f[b * NFC * TT + (c0 + r) * TT + col];
    }
    __syncthreads();
    for (int e = threadIdx.x; e < 6400; e += 256) {
        int t = e >> 6, c = e & 63;
        fT[(t * BB + b) * NFC + c0 + c] = L[c][t];
    }
}

// ---------------- frame input network (fp32) ----------------
__global__ __launch_bounds__(256) void fargan_frame(
    const float* __restrict__ fT, const float* __restrict__ gfeat,
    const float* __restrict__ W1, const float* __restrict__ ib1,
    const float* __restrict__ W2, const float* __restrict__ ib2,
    float* __restrict__ xall)
{
    __shared__ __align__(16) float cat[16][ICC];
    __shared__ __align__(16) float zb[16][ICC];
    const int tid = threadIdx.x;
    const int t = blockIdx.x >> 2;
    const int q = blockIdx.x & 3;

    for (int bb = 0; bb < 16; ++bb) {
        int b = q * 16 + bb;
        for (int c = tid; c < ICC; c += 256) {
            float v = (c < NFC) ? fT[(t * BB + b) * NFC + c]
                                : gfeat[b * GCC + (c - NFC)];
            cat[bb][c] = v;
        }
    }
    __syncthreads();

    {
        int rg = tid & 63, bg = tid >> 6;
        int n0 = rg * 8, bb0 = bg * 4;
        float acc[8][4];
#pragma unroll
        for (int r = 0; r < 8; ++r)
#pragma unroll
            for (int j = 0; j < 4; ++j) acc[r][j] = 0.f;
        for (int k = 0; k < ICC; k += 4) {
            float4 cv[4];
#pragma unroll
            for (int j = 0; j < 4; ++j) cv[j] = *(const float4*)&cat[bb0 + j][k];
#pragma unroll
            for (int r = 0; r < 8; ++r) {
                float4 wv = *(const float4*)&W1[(n0 + r) * ICC + k];
#pragma unroll
                for (int j = 0; j < 4; ++j)
                    acc[r][j] += wv.x * cv[j].x + wv.y * cv[j].y + wv.z * cv[j].z + wv.w * cv[j].w;
            }
        }
#pragma unroll
        for (int r = 0; r < 8; ++r) {
            float bias = ib1[n0 + r];
#pragma unroll
            for (int j = 0; j < 4; ++j)
                zb[bb0 + j][n0 + r] = tanhf(acc[r][j] + bias);
        }
    }
    __syncthreads();

    {
        int rg = tid & 63, bg = tid >> 6;
        int n0 = rg * 4, bb0 = bg * 4;
        float acc[4][4];
#pragma unroll
        for (int r = 0; r < 4; ++r)
#pragma unroll
            for (int j = 0; j < 4; ++j) acc[r][j] = 0.f;
        for (int k = 0; k < ICC; k += 4) {
            float4 cv[4];
#pragma unroll
            for (int j = 0; j < 4; ++j) cv[j] = *(const float4*)&zb[bb0 + j][k];
#pragma unroll
            for (int r = 0; r < 4; ++r) {
                float4 wv = *(const float4*)&W2[(n0 + r) * ICC + k];
#pragma unroll
                for (int j = 0; j < 4; ++j)
                    acc[r][j] += wv.x * cv[j].x + wv.y * cv[j].y + wv.z * cv[j].z + wv.w * cv[j].w;
            }
        }
#pragma unroll
        for (int r = 0; r < 4; ++r) {
            float bias = ib2[n0 + r];
#pragma unroll
            for (int j = 0; j < 4; ++j) {
                int b = q * 16 + bb0 + j;
                xall[(t * BB + b) * HOPC + n0 + r] = acc[r][j] + bias;
            }
        }
    }
}

// ---------------- uniform pre-generation ----------------
__global__ __launch_bounds__(256) void fargan_ugen(float* __restrict__ ug) {
    __shared__ uint32_t kk[20];
    const int idx = blockIdx.x;
    const int tid = threadIdx.x;
    if (tid < 10) {
        uint32_t f0, f1; tf2x32(0u, 1u, 0u, (uint32_t)idx, f0, f1);
        uint32_t A, Bv;  tf2x32(f0, f1, 0u, (uint32_t)tid, A, Bv);
        kk[2 * tid] = A; kk[2 * tid + 1] = Bv;
    }
    __syncthreads();
    float* dst = ug + (size_t)idx * 64 * 704;
    for (int c = 0; c < 64; ++c) {
        for (int j = tid; j < 704; j += 256) {
            int sl = j >> 6;
            int kx = (sl < 9) ? 2 * sl : 18;
            uint32_t m = (sl < 9) ? (uint32_t)(c * 64 + (j & 63))
                                  : (uint32_t)(c * 128 + (j - 576));
            dst[c * 704 + j] = unifP(kk[kx], kk[kx + 1], m);
        }
    }
}

// ---------------- sequential chain, MFMA engine ------------------------------
// v11: every matvec stage is mfma_f32_16x16x32_f16 with B broadcast into all
// 16 cols (one ds_read_b128 per k-chunk). Waves 0-3 own the 3 GRUs' gate
// tiles for their 16-row group (ah MFMAs front-loaded into the FW1 segment);
// waves 4-7 own FW1/FW2/GLU1-3/OUT; SKIP/SG split over all 8 waves.
// Activation work split across the 16 redundant cols (lane processes row
// l&3 of its 4-row subgroup; cols 0-3 write). skip_dense staged in padded
// dynamic LDS (stride 328 halves). 11 barriers, f32 carry points preserved
// (tw in regs, hNv via HNF, sp via SPN, o in regs, xs via XSO).
__global__ __launch_bounds__(512) void fargan_seqmf(
    const float* __restrict__ xall, const f16* __restrict__ wh,
    const float* __restrict__ ug, float* __restrict__ outp)
{
    const int tid = threadIdx.x;
    const int w = tid >> 6;         // wave 0..7
    const int l = tid & 63;
    const int bg = blockIdx.x;
    const int rsel = l & 3;
    const int subg = (l >> 4) << 2; // 0,4,8,12

    __shared__ __align__(16) f16 XH[128];
    __shared__ __align__(16) f16 SKXH[320];
    __shared__ __align__(16) f16 TWH[64];
    __shared__ __align__(16) f16 HNH[64];
    __shared__ __align__(16) float HNF[64];
    __shared__ __align__(16) f16 SPNH[128];
    __shared__ __align__(16) float SPN[128];
    __shared__ __align__(16) f16 SKVH[128];
    __shared__ __align__(16) f16 HH[2][3][64];
    __shared__ __align__(16) float Hf[2][3][64];
    __shared__ __align__(16) float UNF[2][704];
    __shared__ __align__(16) float XSO[64];
    extern __shared__ __align__(16) f16 SKW[];   // [128][SKW_STRIDE] skip_dense

    const f32x4v z4 = {0.f, 0.f, 0.f, 0.f};

    // ---- persistent weight fragments (register/AGPR resident)
    f16x8v aiW[3][3][4], ahW[3][3][2];            // waves 0-3
    f16x8v f1W[4], f2W[2], glW[3][2], outW[4];    // waves 4-7
    f16x8v sgW[4];                                // all waves
    if (w < 4) {
        const int q = w;
        const int GIH[3] = {OFF_G1IH, OFF_G2IH, OFF_G3IH};
        const int GHH[3] = {OFF_G1HH, OFF_G2HH, OFF_G3HH};
#pragma unroll
        for (int GI = 0; GI < 3; ++GI)
#pragma unroll
            for (int gt = 0; gt < 3; ++gt) {
#pragma unroll
                for (int kc = 0; kc < 4; ++kc)
                    aiW[GI][gt][kc] = ldfragG(wh + GIH[GI], 128, gt * 64 + q * 16, kc, l);
#pragma unroll
                for (int kc = 0; kc < 2; ++kc)
                    ahW[GI][gt][kc] = ldfragG(wh + GHH[GI], 64, gt * 64 + q * 16, kc, l);
            }
    } else {
        const int u = w - 4;
        const int GLU[3] = {OFF_GLU1, OFF_GLU2, OFF_GLU3};
#pragma unroll
        for (int kc = 0; kc < 4; ++kc) f1W[kc] = ldfragG(wh + OFF_FW, 128, u * 16, kc, l);
#pragma unroll
        for (int kc = 0; kc < 2; ++kc) f2W[kc] = ldfragG(wh + OFF_FWGLU, 64, u * 16, kc, l);
#pragma unroll
        for (int GI = 0; GI < 3; ++GI)
#pragma unroll
            for (int kc = 0; kc < 2; ++kc)
                glW[GI][kc] = ldfragG(wh + GLU[GI], 64, u * 16, kc, l);
#pragma unroll
        for (int kc = 0; kc < 4; ++kc) outW[kc] = ldfragG(wh + OFF_OUT, 128, u * 16, kc, l);
    }
#pragma unroll
    for (int kc = 0; kc < 4; ++kc) sgW[kc] = ldfragG(wh + OFF_SKIPG, 128, w * 16, kc, l);

    // ---- stage skip_dense into padded LDS (row stride 328 halves)
    for (int e = tid; e < 128 * 40; e += NTHR) {
        int r = e / 40, c8 = e - r * 40;
        *(f16x8v*)&SKW[r * SKW_STRIDE + c8 * 8] =
            *(const f16x8v*)(wh + OFF_SKIPD + r * 320 + c8 * 8);
    }

    // ---- init state
    if (tid < 64) {
        XSO[tid] = 0.f; XH[tid] = (f16)0.f; XH[64 + tid] = (f16)0.f;
#pragma unroll
        for (int GI = 0; GI < 3; ++GI) { Hf[0][GI][tid] = 0.f; HH[0][GI][tid] = (f16)0.f; }
    }
    for (int j = tid; j < 704; j += NTHR) UNF[0][j] = ug[(size_t)bg * 704 + j];
    __syncthreads();
    if (tid < 64) SKXH[256 + tid] = (f16)noiseu(0.f, UNF[0][64 + tid]);

    float xf0 = xall[(0 * BB + bg) * HOPC + 0 * SS + (tid & 63)];
    float xf1 = xall[(0 * BB + bg) * HOPC + 1 * SS + (tid & 63)];
    float xf2 = xall[(0 * BB + bg) * HOPC + 2 * SS + (tid & 63)];
    float xf3 = xall[(0 * BB + bg) * HOPC + 3 * SS + (tid & 63)];
    __syncthreads();

    for (int t = 0; t < TT; ++t) {
        const int tn = (t + 1 < TT) ? t + 1 : t;
        float xn0 = xall[(tn * BB + bg) * HOPC + 0 * SS + (tid & 63)];
        float xn1 = xall[(tn * BB + bg) * HOPC + 1 * SS + (tid & 63)];
        float xn2 = xall[(tn * BB + bg) * HOPC + 2 * SS + (tid & 63)];
        float xn3 = xall[(tn * BB + bg) * HOPC + 3 * SS + (tid & 63)];

        for (int s = 0; s < 4; ++s) {
            const int idx = t * 4 + s;
            const int p = idx & 1;
            float gl0, gl1, twv = 0.f;
            f32x4v accRZ[3][2], accHN[3];
            f16x8v skW[10];

            // ======== S1: input noise (tid<64)                    [B1]
            if (tid < 64) {
                float u0 = UNF[p][tid];
                float xv = (s == 0) ? xf0 : (s == 1) ? xf1 : (s == 2) ? xf2 : xf3;
                float xs = noiseu(xv, u0);
                float old = XSO[tid];
                XSO[tid] = xs;
                XH[tid] = (f16)xs; XH[64 + tid] = (f16)old;
            }
            bar_lds();

            // ======== S2: FW1 (w>=4) | ah-frontload (w<4)         [B2]
            {
                const int idn = (idx + 1 < 400) ? idx + 1 : 399;
                const float* gsrc = ug + ((size_t)idn * 64 + bg) * 704;
                gl0 = gsrc[tid];
                gl1 = (tid < 192) ? gsrc[512 + tid] : 0.f;
            }
            if (w >= 4) {
                const int u = w - 4;
                f32x4v acc = z4;
#pragma unroll
                for (int kc = 0; kc < 4; ++kc)
                    acc = MFMA16(f1W[kc], ldbL(&XH[kc * 32], l), acc);
                twv = tanhfast(sel4(acc, rsel));
                if ((l & 12) == 0) TWH[u * 16 + subg + rsel] = (f16)twv;
            } else {
#pragma unroll
                for (int GI = 0; GI < 3; ++GI) {
                    f16x8v b0 = ldbL(&HH[p][GI][0], l), b1 = ldbL(&HH[p][GI][32], l);
                    accRZ[GI][0] = MFMA16(ahW[GI][0][1], b1, MFMA16(ahW[GI][0][0], b0, z4));
                    accRZ[GI][1] = MFMA16(ahW[GI][1][1], b1, MFMA16(ahW[GI][1][0], b0, z4));
                    accHN[GI]    = MFMA16(ahW[GI][2][1], b1, MFMA16(ahW[GI][2][0], b0, z4));
                }
            }
            bar_lds();

            // ======== S3: FW2 (w>=4)                              [B3]
            if (w >= 4) {
                const int u = w - 4;
                f32x4v acc = MFMA16(f2W[1], ldbL(&TWH[32], l),
                                    MFMA16(f2W[0], ldbL(&TWH[0], l), z4));
                const int ROW = u * 16 + subg + rsel;
                float fv = noiseu(twv * sigmf(sel4(acc, rsel)), UNF[p][128 + ROW]);
                if ((l & 12) == 0) SKXH[192 + ROW] = (f16)fv;
            }
            bar_lds();

            // ======== GRU cores (w<4) and GLUs (w>=4)
#define GRU_CORE(GI, B0, B1, B2, B3, UH)                                                    \
            if (w < 4) {                                                                    \
                f16x8v b0 = ldbL(&SKXH[B0], l), b1 = ldbL(&SKXH[B1], l);                    \
                f16x8v b2 = ldbL(&SKXH[B2], l), b3 = ldbL(&SKXH[B3], l);                    \
                f32x4v aR = accRZ[GI][0], aZ = accRZ[GI][1], aN = z4;                       \
                aR = MFMA16(aiW[GI][0][0], b0, aR); aR = MFMA16(aiW[GI][0][1], b1, aR);     \
                aR = MFMA16(aiW[GI][0][2], b2, aR); aR = MFMA16(aiW[GI][0][3], b3, aR);     \
                aZ = MFMA16(aiW[GI][1][0], b0, aZ); aZ = MFMA16(aiW[GI][1][1], b1, aZ);     \
                aZ = MFMA16(aiW[GI][1][2], b2, aZ); aZ = MFMA16(aiW[GI][1][3], b3, aZ);     \
                aN = MFMA16(aiW[GI][2][0], b0, aN); aN = MFMA16(aiW[GI][2][1], b1, aN);     \
                aN = MFMA16(aiW[GI][2][2], b2, aN); aN = MFMA16(aiW[GI][2][3], b3, aN);     \
                const int ROW = w * 16 + subg + rsel;                                       \
                float vr = sel4(aR, rsel), vz = sel4(aZ, rsel);                             \
                float vin = sel4(aN, rsel), vhn = sel4(accHN[GI], rsel);                    \
                float hold = Hf[p][GI][ROW];                                                \
                float rr = sigmf(vr), zz = sigmf(vz);                                       \
                float nn = tanhfast(vin + rr * vhn);                                        \
                float hnew = (1.f - zz) * nn + zz * hold;                                   \
                float hNv = noiseu(hnew, UNF[p][(UH) + ROW]);                               \
                if ((l & 12) == 0) {                                                        \
                    Hf[p ^ 1][GI][ROW] = hnew;                                              \
                    HH[p ^ 1][GI][ROW] = (f16)hnew;                                         \
                    HNH[ROW] = (f16)hNv;                                                    \
                    HNF[ROW] = hNv;                                                         \
                }                                                                           \
            }                                                                               \
            bar_lds();

#define GLU_SEG(GI, GOFF, UG_, EXTRA)                                                       \
            EXTRA;                                                                          \
            if (w >= 4) {                                                                   \
                const int u = w - 4;                                                        \
                f32x4v acc = MFMA16(glW[GI][1], ldbL(&HNH[32], l),                          \
                                    MFMA16(glW[GI][0], ldbL(&HNH[0], l), z4));              \
                const int ROW = u * 16 + subg + rsel;                                       \
                float val = noiseu(HNF[ROW] * sigmf(sel4(acc, rsel)),                       \
                                   UNF[p][(UG_) + ROW]);                                    \
                if ((l & 12) == 0) SKXH[(GOFF) + ROW] = (f16)val;                           \
            }                                                                               \
            bar_lds();

#define S7EXTRA do {                                                                        \
                UNF[p ^ 1][tid] = gl0;                                                      \
                if (tid < 192) UNF[p ^ 1][512 + tid] = gl1;                                 \
                _Pragma("unroll")                                                           \
                for (int kc = 0; kc < 10; ++kc)                                             \
                    skW[kc] = *(const f16x8v*)&SKW[(w * 16 + (l & 15)) * SKW_STRIDE         \
                                                   + kc * 32 + ((l >> 4) << 3)];            \
            } while (0)

            GRU_CORE(0, 192, 224, 256, 288, 192)   // S4 [B4]
            GLU_SEG(0, 0, 256, ((void)0))          // S5 [B5]
            GRU_CORE(1, 0, 32, 256, 288, 320)      // S6 [B6]
            GLU_SEG(1, 64, 384, S7EXTRA)           // S7 [B7]
            GRU_CORE(2, 64, 96, 256, 288, 448)     // S8 [B8]
            GLU_SEG(2, 128, 512, ((void)0))        // S9 [B9]
#undef GRU_CORE
#undef GLU_SEG
#undef S7EXTRA

            // ======== S10: SKIP (all waves, tile w)               [B10]
            {
                f32x4v acc = z4;
#pragma unroll
                for (int kc = 0; kc < 10; ++kc)
                    acc = MFMA16(skW[kc], ldbL(&SKXH[kc * 32], l), acc);
                const int ROW = w * 16 + subg + rsel;
                float sp = noiseu(tanhfast(sel4(acc, rsel)), UNF[p][576 + ROW]);
                if ((l & 12) == 0) { SPNH[ROW] = (f16)sp; SPN[ROW] = sp; }
            }
            bar_lds();

            // ======== S11: SG (all waves, tile w)                 [B11]
            {
                f32x4v acc = z4;
#pragma unroll
                for (int kc = 0; kc < 4; ++kc)
                    acc = MFMA16(sgW[kc], ldbL(&SPNH[kc * 32], l), acc);
                const int ROW = w * 16 + subg + rsel;
                float sk = SPN[ROW] * sigmf(sel4(acc, rsel));
                if ((l & 12) == 0) SKVH[ROW] = (f16)sk;
            }
            bar_lds();

            // ======== S12: OUT (w>=4)  [no barrier; B1 of next step orders]
            if (w >= 4) {
                const int u = w - 4;
                f32x4v acc = z4;
#pragma unroll
                for (int kc = 0; kc < 4; ++kc)
                    acc = MFMA16(outW[kc], ldbL(&SKVH[kc * 32], l), acc);
                const int ROW = u * 16 + subg + rsel;
                float o = tanhfast(sel4(acc, rsel));
                float pn = noiseu(o, UNF[p ^ 1][64 + ROW]);
                if ((l & 12) == 0) {
                    outp[bg * (TT * HOPC) + t * HOPC + s * SS + ROW] = o;
                    SKXH[256 + ROW] = (f16)pn;
                }
            }
        }
        xf0 = xn0; xf1 = xn1; xf2 = xn2; xf3 = xn3;
    }
}

// ---------------- fallback: v4 sequential chain (in-kernel threefry) --------
__global__ __launch_bounds__(512) void fargan_seq(
    const float* __restrict__ xall, const f16* __restrict__ wh,
    float* __restrict__ outp)
{
    const int tid = threadIdx.x;
    const int row = tid >> 3;
    const int g = tid & 7;
    const int bg = blockIdx.x;

    __shared__ __align__(16) f16 XH[128];
    __shared__ __align__(16) f16 SKXH[320];
    __shared__ __align__(16) f16 TWH[64], HNH[64];
    __shared__ __align__(16) f16 SPNH[128], SKVH[128];
    __shared__ __align__(16) f16 HH[2][3][64];
    __shared__ __align__(16) float Hf[2][3][64];
    __shared__ __align__(16) float UNF[2][704];
    __shared__ uint32_t KK[401][20];

    WF1 rF1;  ldF1(wh + OFF_FW, row, g, rF1);
    U16 rF2;  ldF2(wh + OFF_FWGLU, row, g, rF2);
    WGRU rG1; ldGRU(wh + OFF_G1IH, wh + OFF_G1HH, wh + OFF_GLU1, row, g, rG1);
    WGRU rG2; ldGRU(wh + OFF_G2IH, wh + OFF_G2HH, wh + OFF_GLU2, row, g, rG2);
    WGRU rG3; ldGRU(wh + OFF_G3IH, wh + OFF_G3HH, wh + OFF_GLU3, row, g, rG3);
    WSG rSG;  ldSG(wh + OFF_SKIPG, row, g, rSG);
    WF1 rOUT; ldF1(wh + OFF_OUT, row, g, rOUT);

    pinU(rF1.w[0]); pinU(rF1.w[1]); pinU(rF2);
#pragma unroll
    for (int j = 0; j < 6; ++j) { pinU(rG1.wih[j]); pinU(rG2.wih[j]); pinU(rG3.wih[j]); }
#pragma unroll
    for (int j = 0; j < 3; ++j) { pinU(rG1.whh[j]); pinU(rG2.whh[j]); pinU(rG3.whh[j]); }
    pinU(rG1.glu); pinU(rG2.glu); pinU(rG3.glu);
#pragma unroll
    for (int j = 0; j < 4; ++j) pinU(rSG.w[j]);
    pinU(rOUT.w[0]); pinU(rOUT.w[1]);

    float prevO = 0.f, xs_old = 0.f;
    if (g == 0) {
#pragma unroll
        for (int i = 0; i < 3; ++i) { Hf[0][i][row] = 0.f; HH[0][i][row] = (f16)0.f; }
        XH[row] = (f16)0.f; XH[64 + row] = (f16)0.f;
    }

    for (int e = tid; e < 4010; e += NTHR) {
        int ii = e / 10, ki = e - ii * 10;
        uint32_t f0, f1; tf2x32(0u, 1u, 0u, (uint32_t)ii, f0, f1);
        uint32_t A, Bv;  tf2x32(f0, f1, 0u, (uint32_t)ki, A, Bv);
        KK[ii][2 * ki] = A; KK[ii][2 * ki + 1] = Bv;
    }
    __syncthreads();

    for (int j = tid; j < 704; j += NTHR) {
        int sl = j >> 6;
        int kx = (sl < 9) ? 2 * sl : 18;
        uint32_t m = (sl < 9) ? (uint32_t)(bg * 64 + (j & 63))
                              : (uint32_t)(bg * 128 + (j - 576));
        UNF[0][j] = unifP(KK[0][kx], KK[0][kx + 1], m);
    }

    float xf0 = xall[(0 * BB + bg) * HOPC + 0 * SS + row];
    float xf1 = xall[(0 * BB + bg) * HOPC + 1 * SS + row];
    float xf2 = xall[(0 * BB + bg) * HOPC + 2 * SS + row];
    float xf3 = xall[(0 * BB + bg) * HOPC + 3 * SS + row];
    __syncthreads();

    for (int t = 0; t < TT; ++t) {
        const int tn = (t + 1 < TT) ? t + 1 : t;
        float xn0 = xall[(tn * BB + bg) * HOPC + 0 * SS + row];
        float xn1 = xall[(tn * BB + bg) * HOPC + 1 * SS + row];
        float xn2 = xall[(tn * BB + bg) * HOPC + 2 * SS + row];
        float xn3 = xall[(tn * BB + bg) * HOPC + 3 * SS + row];

        for (int s = 0; s < 4; ++s) {
            const int idx = t * 4 + s;
            const int p = idx & 1;

            if (g == 0) {
                float u0 = UNF[p][row];
                float u1 = UNF[p][64 + row];
                float xv = (s == 0) ? xf0 : (s == 1) ? xf1 : (s == 2) ? xf2 : xf3;
                float xs = noiseu(xv, u0);
                XH[row] = (f16)xs; XH[64 + row] = (f16)xs_old; xs_old = xs;
                SKXH[256 + row] = (f16)noiseu(prevO, u1);
            }
            bar_lds();

            float twv;
            {
                U16 xa, xb;
                xa.u = *(const uint4*)&XH[g * 16];
                xb.u = *(const uint4*)&XH[g * 16 + 8];
                float a = dotU(rF1.w[0], xa, 0.f);
                a = dotU(rF1.w[1], xb, a);
                twv = tanhfast(red8dpp(a));
                if (g == 0) TWH[row] = (f16)twv;
            }
            bar_lds();

            {
                U16 xa; xa.u = *(const uint4*)&TWH[g * 8];
                if (tid < 256) {
                    int kx = 2 * (tid >> 6);
                    UNF[p ^ 1][tid] = unifP(KK[idx + 1][kx], KK[idx + 1][kx + 1],
                                            (uint32_t)(bg * 64 + (tid & 63)));
                }
                float a = red8dpp(dotU(rF2, xa, 0.f));
                if (g == 0) SKXH[192 + row] = (f16)noiseu(twv * sigmf(a), UNF[p][128 + row]);
            }
            bar_lds();

#define GRU_STEP(RG, XPTR, GI, UH, UG_, GOFF, EXTRA)                                        \
            {                                                                               \
                const f16* xin = (XPTR);                                                    \
                U16 xa, xb, xh;                                                             \
                xa.u = *(const uint4*)xin;                                                  \
                xb.u = *(const uint4*)(xin + 8);                                            \
                xh.u = *(const uint4*)&HH[p][GI][g * 8];                                    \
                EXTRA;                                                                      \
                float ai0 = 0, ai1 = 0, ai2 = 0, ah0 = 0, ah1 = 0, ah2 = 0;                 \
                ai0 = dotU(RG.wih[0], xa, ai0); ai0 = dotU(RG.wih[1], xb, ai0);             \
                ai1 = dotU(RG.wih[2], xa, ai1); ai1 = dotU(RG.wih[3], xb, ai1);             \
                ai2 = dotU(RG.wih[4], xa, ai2); ai2 = dotU(RG.wih[5], xb, ai2);             \
                ah0 = dotU(RG.whh[0], xh, ah0);                                             \
                ah1 = dotU(RG.whh[1], xh, ah1);                                             \
                ah2 = dotU(RG.whh[2], xh, ah2);                                             \
                ai0 = red8dpp(ai0); ai1 = red8dpp(ai1); ai2 = red8dpp(ai2);                 \
                ah0 = red8dpp(ah0); ah1 = red8dpp(ah1); ah2 = red8dpp(ah2);                 \
                float hold = Hf[p][GI][row];                                                \
                float r  = sigmf(ai0 + ah0);                                                \
                float z  = sigmf(ai1 + ah1);                                                \
                float nn = tanhfast(ai2 + r * ah2);                                         \
                float hnew = (1.f - z) * nn + z * hold;                                     \
                float hNv = noiseu(hnew, UNF[p][(UH) + row]);                               \
                if (g == 0) {                                                               \
                    Hf[p ^ 1][GI][row] = hnew;                                              \
                    HH[p ^ 1][GI][row] = (f16)hnew;                                         \
                    HNH[row] = (f16)hNv;                                                    \
                }                                                                           \
                bar_lds();                                                                  \
                U16 xg; xg.u = *(const uint4*)&HNH[g * 8];                                  \
                float ag = red8dpp(dotU(RG.glu, xg, 0.f));                                  \
                if (g == 0) SKXH[(GOFF) + row] =                                            \
                    (f16)noiseu(hNv * sigmf(ag), UNF[p][(UG_) + row]);                      \
            }                                                                               \
            bar_lds();

#define NOISE_A2 do { if (tid >= 256) {                                                     \
                int kx = 2 * (tid >> 6);                                                    \
                UNF[p ^ 1][tid] = unifP(KK[idx + 1][kx], KK[idx + 1][kx + 1],               \
                                        (uint32_t)(bg * 64 + (tid & 63))); } } while (0)
#define NOISE_B do { int j2 = tid + 512; if (j2 < 704) {                                    \
                int kx = (j2 < 576) ? 16 : 18;                                              \
                uint32_t m2 = (j2 < 576) ? (uint32_t)(bg * 64 + (j2 & 63))                  \
                                         : (uint32_t)(bg * 128 + (j2 - 576));               \
                UNF[p ^ 1][j2] = unifP(KK[idx + 1][kx], KK[idx + 1][kx + 1], m2); } } while (0)

            GRU_STEP(rG1, SKXH + 192 + g * 16, 0, 192, 256, 0, NOISE_A2)
            GRU_STEP(rG2, (g < 4 ? SKXH + g * 16 : SKXH + 256 + (g - 4) * 16), 1, 320, 384, 64, NOISE_B)
            WSK rSK; ldSK(wh + OFF_SKIPD, row, g, rSK);
            GRU_STEP(rG3, (g < 4 ? SKXH + 64 + g * 16 : SKXH + 256 + (g - 4) * 16), 2, 448, 512, 128, ((void)0))
#undef GRU_STEP
#undef NOISE_A2
#undef NOISE_B

            float sp0, sp1;
            {
                U16 xs[5];
#pragma unroll
                for (int i = 0; i < 5; ++i) xs[i].u = *(const uint4*)&SKXH[g * 40 + 8 * i];
                float a0 = 0, a1 = 0;
#pragma unroll
                for (int i = 0; i < 5; ++i) {
                    a0 = dotU(rSK.w[i], xs[i], a0);
                    a1 = dotU(rSK.w[5 + i], xs[i], a1);
                }
                sp0 = noiseu(tanhfast(red8dpp(a0)), UNF[p][576 + row]);
                sp1 = noiseu(tanhfast(red8dpp(a1)), UNF[p][640 + row]);
                if (g == 0) { SPNH[row] = (f16)sp0; SPNH[64 + row] = (f16)sp1; }
            }
            bar_lds();

            {
                U16 xa, xb;
                xa.u = *(const uint4*)&SPNH[g * 16];
                xb.u = *(const uint4*)&SPNH[g * 16 + 8];
                float a0 = dotU(rSG.w[0], xa, 0.f); a0 = dotU(rSG.w[1], xb, a0);
                float a1 = dotU(rSG.w[2], xa, 0.f); a1 = dotU(rSG.w[3], xb, a1);
                a0 = red8dpp(a0); a1 = red8dpp(a1);
                if (g == 0) {
                    SKVH[row]      = (f16)(sp0 * sigmf(a0));
                    SKVH[64 + row] = (f16)(sp1 * sigmf(a1));
                }
            }
            bar_lds();

            {
                U16 xa, xb;
                xa.u = *(const uint4*)&SKVH[g * 16];
                xb.u = *(const uint4*)&SKVH[g * 16 + 8];
                float a = dotU(rOUT.w[0], xa, 0.f);
                a = dotU(rOUT.w[1], xb, a);
                float o = tanhfast(red8dpp(a));
                prevO = o;
                if (g == 0) outp[bg * (TT * HOPC) + t * HOPC + s * SS + row] = o;
            }
        }
        xf0 = xn0; xf1 = xn1; xf2 = xn2; xf3 = xn3;
    }
}

extern "C" void kernel_launch(void* const* d_in, const int* in_sizes, int n_in,
                              void* d_out, int out_size, void* d_ws, size_t ws_size,
                              hipStream_t stream) {
    const float* features = (const float*)d_in[0];
    const float* gfeat    = (const float*)d_in[1];
    const float* W1       = (const float*)d_in[2];
    const float* ib1      = (const float*)d_in[3];
    const float* W2       = (const float*)d_in[4];
    const float* ib2      = (const float*)d_in[5];

    float* xall = (float*)d_ws;                    // 6.55 MB
    float* fT   = xall + XALL_F32;                 // 6.55 MB
    f16*   wh   = (f16*)(fT + XALL_F32);           // 0.40 MB
    float* ug   = (float*)(wh + W_TOTAL);          // 72.1 MB (if ws permits)
    float* outp = (float*)d_out;

    const size_t need = (size_t)13508608 + UG_FLOATS * 4;
    const bool pregen = (ws_size >= need);

    SrcW sw;
    for (int i = 0; i < 14; ++i) sw.p[i] = (const float*)d_in[6 + i];

    hipLaunchKernelGGL(fargan_cvtw, dim3((W_TOTAL + 255) / 256), dim3(256), 0, stream, sw, wh);
    hipLaunchKernelGGL(fargan_tr, dim3(256), dim3(256), 0, stream, features, fT);
    hipLaunchKernelGGL(fargan_frame, dim3(TT * 4), dim3(256), 0, stream,
                       fT, gfeat, W1, ib1, W2, ib2, xall);
    if (pregen) {
        hipLaunchKernelGGL(fargan_ugen, dim3(400), dim3(256), 0, stream, ug);
        hipLaunchKernelGGL(fargan_seqmf, dim3(NBLK), dim3(NTHR),
                           128 * SKW_STRIDE * sizeof(f16), stream,
                           xall, wh, ug, outp);
    } else {
        hipLaunchKernelGGL(fargan_seq, dim3(NBLK), dim3(NTHR), 0, stream, xall, wh, outp);
    }
}

// Round 12
// 2362.637 us; speedup vs baseline: 1.7530x; 1.7530x over previous
//
#include <hip/hip_runtime.h>
#include <stdint.h>

#define SS 64
#define BB 64
#define TT 100
#define HOPC 256
#define NFC 256
#define GCC 256
#define ICC 512
#define NC (1.0f/127.0f)
#define NBLK 64       // one block per chain
#define NTHR 512      // 8 waves: lane = (row, g), row=tid>>3, g=tid&7

// f16 weight arena offsets (in halves; same order as inputs 6..19)
#define OFF_FW     0
#define OFF_FWGLU  8192
#define OFF_G1IH   12288
#define OFF_G1HH   36864
#define OFF_GLU1   49152
#define OFF_G2IH   53248
#define OFF_G2HH   77824
#define OFF_GLU2   90112
#define OFF_G3IH   94208
#define OFF_G3HH   118784
#define OFF_GLU3   131072
#define OFF_SKIPD  135168
#define OFF_SKIPG  176128
#define OFF_OUT    192512
#define W_TOTAL    200704
#define XALL_F32   (TT * BB * HOPC)   // 1,638,400 floats
#define UG_FLOATS  ((size_t)400 * 64 * 704)   // 18,022,400 floats = 72.1 MB

typedef _Float16 f16;
typedef _Float16 h2 __attribute__((ext_vector_type(2)));
union U16 { uint4 u; h2 h[4]; };

#if __has_builtin(__builtin_amdgcn_fdot2)
#define FDOT2(a, b, c) __builtin_amdgcn_fdot2((a), (b), (c), false)
#else
#define FDOT2(a, b, c) ((c) + (float)(a)[0] * (float)(b)[0] + (float)(a)[1] * (float)(b)[1])
#endif

// ---------------- threefry2x32 core (Random123-KAT verified) ----------------
__device__ __forceinline__ uint32_t rotl32(uint32_t x, int r) {
    return (x << r) | (x >> (32 - r));
}

__device__ __forceinline__ void tf2x32(uint32_t k0, uint32_t k1, uint32_t c0, uint32_t c1,
                                       uint32_t& o0, uint32_t& o1) {
    uint32_t k2 = k0 ^ k1 ^ 0x1BD11BDAu;
    uint32_t x0 = c0 + k0, x1 = c1 + k1;
    x0 += x1; x1 = rotl32(x1, 13); x1 ^= x0;
    x0 += x1; x1 = rotl32(x1, 15); x1 ^= x0;
    x0 += x1; x1 = rotl32(x1, 26); x1 ^= x0;
    x0 += x1; x1 = rotl32(x1, 6);  x1 ^= x0;
    x0 += k1; x1 += k2 + 1u;
    x0 += x1; x1 = rotl32(x1, 17); x1 ^= x0;
    x0 += x1; x1 = rotl32(x1, 29); x1 ^= x0;
    x0 += x1; x1 = rotl32(x1, 16); x1 ^= x0;
    x0 += x1; x1 = rotl32(x1, 24); x1 ^= x0;
    x0 += k2; x1 += k0 + 2u;
    x0 += x1; x1 = rotl32(x1, 13); x1 ^= x0;
    x0 += x1; x1 = rotl32(x1, 15); x1 ^= x0;
    x0 += x1; x1 = rotl32(x1, 26); x1 ^= x0;
    x0 += x1; x1 = rotl32(x1, 6);  x1 ^= x0;
    x0 += k0; x1 += k1 + 3u;
    x0 += x1; x1 = rotl32(x1, 17); x1 ^= x0;
    x0 += x1; x1 = rotl32(x1, 29); x1 ^= x0;
    x0 += x1; x1 = rotl32(x1, 16); x1 ^= x0;
    x0 += x1; x1 = rotl32(x1, 24); x1 ^= x0;
    x0 += k1; x1 += k2 + 4u;
    x0 += x1; x1 = rotl32(x1, 13); x1 ^= x0;
    x0 += x1; x1 = rotl32(x1, 15); x1 ^= x0;
    x0 += x1; x1 = rotl32(x1, 26); x1 ^= x0;
    x0 += x1; x1 = rotl32(x1, 6);  x1 ^= x0;
    x0 += k2; x1 += k0 + 5u;
    o0 = x0; o1 = x1;
}

// jax_threefry_partitionable semantics: bits(m) = x0^x1 of block (0, m)
__device__ __forceinline__ float unifP(uint32_t k0, uint32_t k1, uint32_t m) {
    uint32_t o0, o1;
    tf2x32(k0, k1, 0u, m, o0, o1);
    uint32_t bits = o0 ^ o1;
    return __uint_as_float((bits >> 9) | 0x3f800000u) - 1.0f;
}

__device__ __forceinline__ float clipf(float v) { return fminf(1.0f, fmaxf(-1.0f, v)); }
__device__ __forceinline__ float noiseu(float v, float u) {
    return clipf(v + (u - 0.5f) * NC);
}
__device__ __forceinline__ float sigmf(float v) {
    return __fdividef(1.0f, 1.0f + __expf(-v));
}
__device__ __forceinline__ float tanhfast(float x) {
    float ax = fminf(fabsf(x), 15.0f);
    float e = __expf(2.0f * ax);
    float r = __fdividef(e - 1.0f, e + 1.0f);
    return copysignf(r, x);
}

// barrier WITHOUT the vmcnt(0) drain __syncthreads() would emit.
__device__ __forceinline__ void bar_lds() {
    asm volatile("s_waitcnt lgkmcnt(0)\n\ts_barrier" ::: "memory");
}

// ---------------- DPP 8-lane reduction (VALU-only, no DS pipe) --------------
__device__ __forceinline__ float red8dpp(float v) {
    int t;
    t = __builtin_amdgcn_update_dpp(0, __float_as_int(v), 0xB1, 0xF, 0xF, true);  // quad xor1
    v += __int_as_float(t);
    t = __builtin_amdgcn_update_dpp(0, __float_as_int(v), 0x4E, 0xF, 0xF, true);  // quad xor2
    v += __int_as_float(t);
    t = __builtin_amdgcn_update_dpp(0, __float_as_int(v), 0x141, 0xF, 0xF, true); // half-row mirror
    v += __int_as_float(t);
    return v;   // all 8 lanes of the group hold the sum
}

// ---------------- f16 dot helper ----------------
__device__ __forceinline__ float dotU(const U16& w, const U16& x, float acc) {
#pragma unroll
    for (int i = 0; i < 4; ++i) acc = FDOT2(w.h[i], x.h[i], acc);
    return acc;
}

// ---------------- register weight structs + loaders ----------------
struct WF1  { U16 w[2]; };                        // K=128, NR=1
struct WGRU { U16 wih[6]; U16 whh[3]; U16 glu; }; // 40 VGPRs
struct WSK  { U16 w[10]; };                       // K=320, NR=2
struct WSG  { U16 w[4]; };                        // K=128, NR=2

__device__ __forceinline__ void ldF1(const f16* W, int row, int g, WF1& r) {
    const f16* p = W + row * 128 + g * 16;
    r.w[0].u = *(const uint4*)p;
    r.w[1].u = *(const uint4*)(p + 8);
}
__device__ __forceinline__ void ldF2(const f16* W, int row, int g, U16& r) {
    r.u = *(const uint4*)(W + row * 64 + g * 8);
}
__device__ __forceinline__ void ldGRU(const f16* Wih, const f16* Whh, const f16* Glu,
                                      int row, int g, WGRU& r) {
#pragma unroll
    for (int j = 0; j < 3; ++j) {
        const f16* p = Wih + (row + 64 * j) * 128 + g * 16;
        r.wih[2 * j].u     = *(const uint4*)p;
        r.wih[2 * j + 1].u = *(const uint4*)(p + 8);
        r.whh[j].u = *(const uint4*)(Whh + (row + 64 * j) * 64 + g * 8);
    }
    r.glu.u = *(const uint4*)(Glu + row * 64 + g * 8);
}
__device__ __forceinline__ void ldSK(const f16* W, int row, int g, WSK& r) {
#pragma unroll
    for (int j = 0; j < 2; ++j) {
        const f16* p = W + (row + 64 * j) * 320 + g * 40;
#pragma unroll
        for (int i = 0; i < 5; ++i) r.w[5 * j + i].u = *(const uint4*)(p + 8 * i);
    }
}
__device__ __forceinline__ void ldSG(const f16* W, int row, int g, WSG& r) {
#pragma unroll
    for (int j = 0; j < 2; ++j) {
        const f16* p = W + (row + 64 * j) * 128 + g * 16;
        r.w[2 * j].u     = *(const uint4*)p;
        r.w[2 * j + 1].u = *(const uint4*)(p + 8);
    }
}

// opaque pin: makes the loaded values asm-defined -> cannot be rematerialized
__device__ __forceinline__ void pinU(U16& r) {
    asm volatile("" : "+v"(r.u.x), "+v"(r.u.y), "+v"(r.u.z), "+v"(r.u.w));
}

// ---------------- weight convert to f16 (flat, same layout) ----------------
struct SrcW { const float* p[14]; };

__global__ __launch_bounds__(256) void fargan_cvtw(SrcW s, f16* __restrict__ dst) {
    const int offs[15] = {0, 8192, 12288, 36864, 49152, 53248, 77824, 90112,
                          94208, 118784, 131072, 135168, 176128, 192512, 200704};
    int i = blockIdx.x * 256 + threadIdx.x;
    if (i >= W_TOTAL) return;
    int sgi = 0;
#pragma unroll
    for (int t = 1; t < 14; ++t) sgi += (i >= offs[t]);
    dst[i] = (f16)s.p[sgi][i - offs[sgi]];
}

// ---------------- feature transpose: f[b][c][t] -> fT[t][b][c] ----------------
__global__ __launch_bounds__(256) void fargan_tr(const float* __restrict__ f,
                                                 float* __restrict__ fT) {
    __shared__ float L[64][104];
    int b = blockIdx.x >> 2, c0 = (blockIdx.x & 3) * 64;
    for (int e = threadIdx.x; e < 6400; e += 256) {
        int r = e / 100, col = e - r * 100;
        L[r][col] = f[b * NFC * TT + (c0 + r) * TT + col];
    }
    __syncthreads();
    for (int e = threadIdx.x; e < 6400; e += 256) {
        int t = e >> 6, c = e & 63;
        fT[(t * BB + b) * NFC + c0 + c] = L[c][t];
    }
}

// ---------------- frame input network v2: LDS-tiled fp32 GEMM ---------------
// v12: the old frame had lane-strided (2KB apart) W loads -> every float4 a
// 64-transaction gather at 1 wave/SIMD; est ~500us of the fixed ~600us gap.
// Now: 800 blocks (t x 8), 8 batches/block; W staged in 64x64 LDS tiles
// (pad 68 floats; rows nq/nq+32 -> conflict-free within a wave), cat/zb in
// padded LDS (516). Same ascending-k fp32 accumulation order as before.
__global__ __launch_bounds__(256) void fargan_frame(
    const float* __restrict__ fT, const float* __restrict__ gfeat,
    const float* __restrict__ W1, const float* __restrict__ ib1,
    const float* __restrict__ W2, const float* __restrict__ ib2,
    float* __restrict__ xall)
{
    __shared__ __align__(16) float catL[8 * 516];
    __shared__ __align__(16) float zbL[8 * 516];
    __shared__ __align__(16) float Wt[64 * 68];
    const int tid = threadIdx.x;
    const int t = blockIdx.x >> 3;
    const int q = blockIdx.x & 7;
    const int b = tid & 7;       // batch within tile
    const int nq = tid >> 3;     // 0..31

    for (int e = tid; e < 8 * 512; e += 256) {
        int bb = e >> 9, c = e & 511;
        float v = (c < NFC) ? fT[(t * BB + q * 8 + bb) * NFC + c]
                            : gfeat[(q * 8 + bb) * GCC + (c - NFC)];
        catL[bb * 516 + c] = v;
    }
    __syncthreads();

    // phase 1: zb = tanh(cat @ W1^T + b1)   (rows n0+nq, n0+nq+32 per thread)
    for (int n0 = 0; n0 < 512; n0 += 64) {
        float a0 = 0.f, a1 = 0.f;
        for (int k0 = 0; k0 < 512; k0 += 64) {
            for (int e = tid; e < 1024; e += 256) {
                int r = e >> 4, c4 = (e & 15) << 2;
                *(float4*)&Wt[r * 68 + c4] =
                    *(const float4*)&W1[(n0 + r) * ICC + k0 + c4];
            }
            __syncthreads();
#pragma unroll
            for (int kc = 0; kc < 16; ++kc) {
                float4 cv = *(const float4*)&catL[b * 516 + k0 + kc * 4];
                float4 w0 = *(const float4*)&Wt[nq * 68 + kc * 4];
                float4 w1 = *(const float4*)&Wt[(nq + 32) * 68 + kc * 4];
                a0 += w0.x * cv.x + w0.y * cv.y + w0.z * cv.z + w0.w * cv.w;
                a1 += w1.x * cv.x + w1.y * cv.y + w1.z * cv.z + w1.w * cv.w;
            }
            __syncthreads();
        }
        zbL[b * 516 + n0 + nq]      = tanhf(a0 + ib1[n0 + nq]);
        zbL[b * 516 + n0 + nq + 32] = tanhf(a1 + ib1[n0 + nq + 32]);
    }
    __syncthreads();

    // phase 2: xall = zb @ W2^T + b2
    for (int n0 = 0; n0 < 256; n0 += 64) {
        float a0 = 0.f, a1 = 0.f;
        for (int k0 = 0; k0 < 512; k0 += 64) {
            for (int e = tid; e < 1024; e += 256) {
                int r = e >> 4, c4 = (e & 15) << 2;
                *(float4*)&Wt[r * 68 + c4] =
                    *(const float4*)&W2[(n0 + r) * ICC + k0 + c4];
            }
            __syncthreads();
#pragma unroll
            for (int kc = 0; kc < 16; ++kc) {
                float4 cv = *(const float4*)&zbL[b * 516 + k0 + kc * 4];
                float4 w0 = *(const float4*)&Wt[nq * 68 + kc * 4];
                float4 w1 = *(const float4*)&Wt[(nq + 32) * 68 + kc * 4];
                a0 += w0.x * cv.x + w0.y * cv.y + w0.z * cv.z + w0.w * cv.w;
                a1 += w1.x * cv.x + w1.y * cv.y + w1.z * cv.z + w1.w * cv.w;
            }
            __syncthreads();
        }
        int B = t * BB + q * 8 + b;
        xall[B * HOPC + n0 + nq]      = a0 + ib2[n0 + nq];
        xall[B * HOPC + n0 + nq + 32] = a1 + ib2[n0 + nq + 32];
    }
}

// ---------------- uniform pre-generation: all steps, all chains --------------
__global__ __launch_bounds__(256) void fargan_ugen(float* __restrict__ ug) {
    __shared__ uint32_t kk[20];
    const int idx = blockIdx.x;
    const int tid = threadIdx.x;
    if (tid < 10) {
        uint32_t f0, f1; tf2x32(0u, 1u, 0u, (uint32_t)idx, f0, f1);
        uint32_t A, Bv;  tf2x32(f0, f1, 0u, (uint32_t)tid, A, Bv);
        kk[2 * tid] = A; kk[2 * tid + 1] = Bv;
    }
    __syncthreads();
    float* dst = ug + (size_t)idx * 64 * 704;
    for (int c = 0; c < 64; ++c) {
        for (int j = tid; j < 704; j += 256) {
            int sl = j >> 6;
            int kx = (sl < 9) ? 2 * sl : 18;
            uint32_t m = (sl < 9) ? (uint32_t)(c * 64 + (j & 63))
                                  : (uint32_t)(c * 128 + (j - 576));
            dst[c * 704 + j] = unifP(kk[kx], kk[kx + 1], m);
        }
    }
}

// ---------------- sequential chain, pre-generated uniforms (v10, verified) --
__global__ __launch_bounds__(512) void fargan_seqpg(
    const float* __restrict__ xall, const f16* __restrict__ wh,
    const float* __restrict__ ug, float* __restrict__ outp)
{
    const int tid = threadIdx.x;
    const int row = tid >> 3;
    const int g = tid & 7;
    const int bg = blockIdx.x;          // chain id

    __shared__ __align__(16) f16 XH[128];          // xsub|s3 mirrors
    __shared__ __align__(16) f16 SKXH[320];        // g1|g2|g3|fw|prevN
    __shared__ __align__(16) f16 TWH[64], HNH[64];
    __shared__ __align__(16) f16 SPNH[128], SKVH[128];
    __shared__ __align__(16) f16 HH[2][3][64];     // GRU state f16 mirrors (ping-pong)
    __shared__ __align__(16) float Hf[2][3][64];   // GRU state fp32 (ping-pong)
    __shared__ __align__(16) float UNF[2][704];    // uniforms, double-buffered by idx&1

    // ---- one-time: register weights (pinned) + init
    WF1 rF1;  ldF1(wh + OFF_FW, row, g, rF1);
    U16 rF2;  ldF2(wh + OFF_FWGLU, row, g, rF2);
    WGRU rG1; ldGRU(wh + OFF_G1IH, wh + OFF_G1HH, wh + OFF_GLU1, row, g, rG1);
    WGRU rG2; ldGRU(wh + OFF_G2IH, wh + OFF_G2HH, wh + OFF_GLU2, row, g, rG2);
    WGRU rG3; ldGRU(wh + OFF_G3IH, wh + OFF_G3HH, wh + OFF_GLU3, row, g, rG3);
    WSG rSG;  ldSG(wh + OFF_SKIPG, row, g, rSG);
    WF1 rOUT; ldF1(wh + OFF_OUT, row, g, rOUT);

    pinU(rF1.w[0]); pinU(rF1.w[1]); pinU(rF2);
#pragma unroll
    for (int j = 0; j < 6; ++j) { pinU(rG1.wih[j]); pinU(rG2.wih[j]); pinU(rG3.wih[j]); }
#pragma unroll
    for (int j = 0; j < 3; ++j) { pinU(rG1.whh[j]); pinU(rG2.whh[j]); pinU(rG3.whh[j]); }
    pinU(rG1.glu); pinU(rG2.glu); pinU(rG3.glu);
#pragma unroll
    for (int j = 0; j < 4; ++j) pinU(rSG.w[j]);
    pinU(rOUT.w[0]); pinU(rOUT.w[1]);

    float prevO = 0.f, xs_old = 0.f;
    if (g == 0) {
#pragma unroll
        for (int i = 0; i < 3; ++i) { Hf[0][i][row] = 0.f; HH[0][i][row] = (f16)0.f; }
        XH[row] = (f16)0.f; XH[64 + row] = (f16)0.f;
    }

    // ---- prologue: uniforms for idx 0 from ug
    for (int j = tid; j < 704; j += NTHR)
        UNF[0][j] = ug[(size_t)bg * 704 + j];

    // ---- prologue: x prefetch for frame 0
    float xf0 = xall[(0 * BB + bg) * HOPC + 0 * SS + row];
    float xf1 = xall[(0 * BB + bg) * HOPC + 1 * SS + row];
    float xf2 = xall[(0 * BB + bg) * HOPC + 2 * SS + row];
    float xf3 = xall[(0 * BB + bg) * HOPC + 3 * SS + row];
    __syncthreads();

    for (int t = 0; t < TT; ++t) {
        // prefetch next frame's x (consumed 4..8 steps from now)
        const int tn = (t + 1 < TT) ? t + 1 : t;
        float xn0 = xall[(tn * BB + bg) * HOPC + 0 * SS + row];
        float xn1 = xall[(tn * BB + bg) * HOPC + 1 * SS + row];
        float xn2 = xall[(tn * BB + bg) * HOPC + 2 * SS + row];
        float xn3 = xall[(tn * BB + bg) * HOPC + 3 * SS + row];

        for (int s = 0; s < 4; ++s) {
            const int idx = t * 4 + s;
            const int p = idx & 1;       // ping-pong parity (H state AND UNF buffer)
            float gl0, gl1;              // next step's uniforms (global->reg->LDS)

            // ======== A (merged with prev OUT): tiny               [barrier 1]
            if (g == 0) {
                float u0 = UNF[p][row];
                float u1 = UNF[p][64 + row];
                float xv = (s == 0) ? xf0 : (s == 1) ? xf1 : (s == 2) ? xf2 : xf3;
                float xs = noiseu(xv, u0);
                XH[row] = (f16)xs; XH[64 + row] = (f16)xs_old; xs_old = xs;
                SKXH[256 + row] = (f16)noiseu(prevO, u1);
            }
            bar_lds();

            // ======== FW1 + issue uniform loads for idx+1          [barrier 2]
            float twv;
            {
                const int idn = (idx + 1 < 400) ? idx + 1 : 399;
                const float* gsrc = ug + ((size_t)idn * 64 + bg) * 704;
                gl0 = gsrc[tid];
                gl1 = (tid < 192) ? gsrc[512 + tid] : 0.f;

                U16 xa, xb;
                xa.u = *(const uint4*)&XH[g * 16];
                xb.u = *(const uint4*)&XH[g * 16 + 8];
                float a = dotU(rF1.w[0], xa, 0.f);
                a = dotU(rF1.w[1], xb, a);
                twv = tanhfast(red8dpp(a));
                if (g == 0) TWH[row] = (f16)twv;
            }
            bar_lds();

            // ======== FW2                                          [barrier 3]
            {
                U16 xa; xa.u = *(const uint4*)&TWH[g * 8];
                float a = red8dpp(dotU(rF2, xa, 0.f));
                if (g == 0) SKXH[192 + row] = (f16)noiseu(twv * sigmf(a), UNF[p][128 + row]);
            }
            bar_lds();

            // ======== GRU+GLU x3 (2 barriers each)
#define GRU_STEP(RG, XPTR, GI, UH, UG_, GOFF, EXTRA)                                        \
            {                                                                               \
                const f16* xin = (XPTR);                                                    \
                U16 xa, xb, xh;                                                             \
                xa.u = *(const uint4*)xin;                                                  \
                xb.u = *(const uint4*)(xin + 8);                                            \
                xh.u = *(const uint4*)&HH[p][GI][g * 8];                                    \
                EXTRA;                                                                      \
                float ai0 = 0, ai1 = 0, ai2 = 0, ah0 = 0, ah1 = 0, ah2 = 0;                 \
                ai0 = dotU(RG.wih[0], xa, ai0); ai0 = dotU(RG.wih[1], xb, ai0);             \
                ai1 = dotU(RG.wih[2], xa, ai1); ai1 = dotU(RG.wih[3], xb, ai1);             \
                ai2 = dotU(RG.wih[4], xa, ai2); ai2 = dotU(RG.wih[5], xb, ai2);             \
                ah0 = dotU(RG.whh[0], xh, ah0);                                             \
                ah1 = dotU(RG.whh[1], xh, ah1);                                             \
                ah2 = dotU(RG.whh[2], xh, ah2);                                             \
                ai0 = red8dpp(ai0); ai1 = red8dpp(ai1); ai2 = red8dpp(ai2);                 \
                ah0 = red8dpp(ah0); ah1 = red8dpp(ah1); ah2 = red8dpp(ah2);                 \
                float hold = Hf[p][GI][row];                                                \
                float r  = sigmf(ai0 + ah0);                                                \
                float z  = sigmf(ai1 + ah1);                                                \
                float nn = tanhfast(ai2 + r * ah2);                                         \
                float hnew = (1.f - z) * nn + z * hold;                                     \
                float hNv = noiseu(hnew, UNF[p][(UH) + row]);                               \
                if (g == 0) {                                                               \
                    Hf[p ^ 1][GI][row] = hnew;                                              \
                    HH[p ^ 1][GI][row] = (f16)hnew;                                         \
                    HNH[row] = (f16)hNv;                                                    \
                }                                                                           \
                bar_lds();                                                                  \
                U16 xg; xg.u = *(const uint4*)&HNH[g * 8];                                  \
                float ag = red8dpp(dotU(RG.glu, xg, 0.f));                                  \
                if (g == 0) SKXH[(GOFF) + row] =                                            \
                    (f16)noiseu(hNv * sigmf(ag), UNF[p][(UG_) + row]);                      \
            }                                                                               \
            bar_lds();

            // store next step's uniforms (loads issued at FW1, long done)
#define UNF_STORE do {                                                                      \
                UNF[p ^ 1][tid] = gl0;                                                      \
                if (tid < 192) UNF[p ^ 1][512 + tid] = gl1; } while (0)

            GRU_STEP(rG1, SKXH + 192 + g * 16, 0, 192, 256, 0, ((void)0))
            GRU_STEP(rG2, (g < 4 ? SKXH + g * 16 : SKXH + 256 + (g - 4) * 16), 1, 320, 384, 64, UNF_STORE)
            WSK rSK; ldSK(wh + OFF_SKIPD, row, g, rSK);   // prefetch skip_dense
            GRU_STEP(rG3, (g < 4 ? SKXH + 64 + g * 16 : SKXH + 256 + (g - 4) * 16), 2, 448, 512, 128, ((void)0))
#undef GRU_STEP
#undef UNF_STORE

            // ======== SKIP: spN = noise(tanh(skip_dense @ SKXH))   [barrier 10]
            float sp0, sp1;
            {
                U16 xs[5];
#pragma unroll
                for (int i = 0; i < 5; ++i) xs[i].u = *(const uint4*)&SKXH[g * 40 + 8 * i];
                float a0 = 0, a1 = 0;
#pragma unroll
                for (int i = 0; i < 5; ++i) {
                    a0 = dotU(rSK.w[i], xs[i], a0);
                    a1 = dotU(rSK.w[5 + i], xs[i], a1);
                }
                sp0 = noiseu(tanhfast(red8dpp(a0)), UNF[p][576 + row]);
                sp1 = noiseu(tanhfast(red8dpp(a1)), UNF[p][640 + row]);
                if (g == 0) { SPNH[row] = (f16)sp0; SPNH[64 + row] = (f16)sp1; }
            }
            bar_lds();

            // ======== SG: skip = spN * sigm(skip_glu @ spN)        [barrier 11]
            {
                U16 xa, xb;
                xa.u = *(const uint4*)&SPNH[g * 16];
                xb.u = *(const uint4*)&SPNH[g * 16 + 8];
                float a0 = dotU(rSG.w[0], xa, 0.f); a0 = dotU(rSG.w[1], xb, a0);
                float a1 = dotU(rSG.w[2], xa, 0.f); a1 = dotU(rSG.w[3], xb, a1);
                a0 = red8dpp(a0); a1 = red8dpp(a1);
                if (g == 0) {
                    SKVH[row]      = (f16)(sp0 * sigmf(a0));
                    SKVH[64 + row] = (f16)(sp1 * sigmf(a1));
                }
            }
            bar_lds();

            // ======== OUT: o = tanh(out_W @ skip)   [no barrier]
            {
                U16 xa, xb;
                xa.u = *(const uint4*)&SKVH[g * 16];
                xb.u = *(const uint4*)&SKVH[g * 16 + 8];
                float a = dotU(rOUT.w[0], xa, 0.f);
                a = dotU(rOUT.w[1], xb, a);
                float o = tanhfast(red8dpp(a));
                prevO = o;
                if (g == 0) outp[bg * (TT * HOPC) + t * HOPC + s * SS + row] = o;
            }
        }
        xf0 = xn0; xf1 = xn1; xf2 = xn2; xf3 = xn3;
    }
}

// ---------------- sequential chain, in-kernel threefry (v4 fallback) --------
__global__ __launch_bounds__(512) void fargan_seq(
    const float* __restrict__ xall, const f16* __restrict__ wh,
    float* __restrict__ outp)
{
    const int tid = threadIdx.x;
    const int row = tid >> 3;
    const int g = tid & 7;
    const int bg = blockIdx.x;          // chain id

    __shared__ __align__(16) f16 XH[128];
    __shared__ __align__(16) f16 SKXH[320];
    __shared__ __align__(16) f16 TWH[64], HNH[64];
    __shared__ __align__(16) f16 SPNH[128], SKVH[128];
    __shared__ __align__(16) f16 HH[2][3][64];
    __shared__ __align__(16) float Hf[2][3][64];
    __shared__ __align__(16) float UNF[2][704];
    __shared__ uint32_t KK[401][20];

    WF1 rF1;  ldF1(wh + OFF_FW, row, g, rF1);
    U16 rF2;  ldF2(wh + OFF_FWGLU, row, g, rF2);
    WGRU rG1; ldGRU(wh + OFF_G1IH, wh + OFF_G1HH, wh + OFF_GLU1, row, g, rG1);
    WGRU rG2; ldGRU(wh + OFF_G2IH, wh + OFF_G2HH, wh + OFF_GLU2, row, g, rG2);
    WGRU rG3; ldGRU(wh + OFF_G3IH, wh + OFF_G3HH, wh + OFF_GLU3, row, g, rG3);
    WSG rSG;  ldSG(wh + OFF_SKIPG, row, g, rSG);
    WF1 rOUT; ldF1(wh + OFF_OUT, row, g, rOUT);

    pinU(rF1.w[0]); pinU(rF1.w[1]); pinU(rF2);
#pragma unroll
    for (int j = 0; j < 6; ++j) { pinU(rG1.wih[j]); pinU(rG2.wih[j]); pinU(rG3.wih[j]); }
#pragma unroll
    for (int j = 0; j < 3; ++j) { pinU(rG1.whh[j]); pinU(rG2.whh[j]); pinU(rG3.whh[j]); }
    pinU(rG1.glu); pinU(rG2.glu); pinU(rG3.glu);
#pragma unroll
    for (int j = 0; j < 4; ++j) pinU(rSG.w[j]);
    pinU(rOUT.w[0]); pinU(rOUT.w[1]);

    float prevO = 0.f, xs_old = 0.f;
    if (g == 0) {
#pragma unroll
        for (int i = 0; i < 3; ++i) { Hf[0][i][row] = 0.f; HH[0][i][row] = (f16)0.f; }
        XH[row] = (f16)0.f; XH[64 + row] = (f16)0.f;
    }

    for (int e = tid; e < 4010; e += NTHR) {
        int ii = e / 10, ki = e - ii * 10;
        uint32_t f0, f1; tf2x32(0u, 1u, 0u, (uint32_t)ii, f0, f1);
        uint32_t A, Bv;  tf2x32(f0, f1, 0u, (uint32_t)ki, A, Bv);
        KK[ii][2 * ki] = A; KK[ii][2 * ki + 1] = Bv;
    }
    __syncthreads();

    for (int j = tid; j < 704; j += NTHR) {
        int sl = j >> 6;
        int kx = (sl < 9) ? 2 * sl : 18;
        uint32_t m = (sl < 9) ? (uint32_t)(bg * 64 + (j & 63))
                              : (uint32_t)(bg * 128 + (j - 576));
        UNF[0][j] = unifP(KK[0][kx], KK[0][kx + 1], m);
    }

    float xf0 = xall[(0 * BB + bg) * HOPC + 0 * SS + row];
    float xf1 = xall[(0 * BB + bg) * HOPC + 1 * SS + row];
    float xf2 = xall[(0 * BB + bg) * HOPC + 2 * SS + row];
    float xf3 = xall[(0 * BB + bg) * HOPC + 3 * SS + row];
    __syncthreads();

    for (int t = 0; t < TT; ++t) {
        const int tn = (t + 1 < TT) ? t + 1 : t;
        float xn0 = xall[(tn * BB + bg) * HOPC + 0 * SS + row];
        float xn1 = xall[(tn * BB + bg) * HOPC + 1 * SS + row];
        float xn2 = xall[(tn * BB + bg) * HOPC + 2 * SS + row];
        float xn3 = xall[(tn * BB + bg) * HOPC + 3 * SS + row];

        for (int s = 0; s < 4; ++s) {
            const int idx = t * 4 + s;
            const int p = idx & 1;

            if (g == 0) {
                float u0 = UNF[p][row];
                float u1 = UNF[p][64 + row];
                float xv = (s == 0) ? xf0 : (s == 1) ? xf1 : (s == 2) ? xf2 : xf3;
                float xs = noiseu(xv, u0);
                XH[row] = (f16)xs; XH[64 + row] = (f16)xs_old; xs_old = xs;
                SKXH[256 + row] = (f16)noiseu(prevO, u1);
            }
            bar_lds();

            float twv;
            {
                U16 xa, xb;
                xa.u = *(const uint4*)&XH[g * 16];
                xb.u = *(const uint4*)&XH[g * 16 + 8];
                float a = dotU(rF1.w[0], xa, 0.f);
                a = dotU(rF1.w[1], xb, a);
                twv = tanhfast(red8dpp(a));
                if (g == 0) TWH[row] = (f16)twv;
            }
            bar_lds();

            {
                U16 xa; xa.u = *(const uint4*)&TWH[g * 8];
                if (tid < 256) {
                    int kx = 2 * (tid >> 6);
                    UNF[p ^ 1][tid] = unifP(KK[idx + 1][kx], KK[idx + 1][kx + 1],
                                            (uint32_t)(bg * 64 + (tid & 63)));
                }
                float a = red8dpp(dotU(rF2, xa, 0.f));
                if (g == 0) SKXH[192 + row] = (f16)noiseu(twv * sigmf(a), UNF[p][128 + row]);
            }
            bar_lds();

#define GRU_STEP(RG, XPTR, GI, UH, UG_, GOFF, EXTRA)                                        \
            {                                                                               \
                const f16* xin = (XPTR);                                                    \
                U16 xa, xb, xh;                                                             \
                xa.u = *(const uint4*)xin;                                                  \
                xb.u = *(const uint4*)(xin + 8);                                            \
                xh.u = *(const uint4*)&HH[p][GI][g * 8];                                    \
                EXTRA;                                                                      \
                float ai0 = 0, ai1 = 0, ai2 = 0, ah0 = 0, ah1 = 0, ah2 = 0;                 \
                ai0 = dotU(RG.wih[0], xa, ai0); ai0 = dotU(RG.wih[1], xb, ai0);             \
                ai1 = dotU(RG.wih[2], xa, ai1); ai1 = dotU(RG.wih[3], xb, ai1);             \
                ai2 = dotU(RG.wih[4], xa, ai2); ai2 = dotU(RG.wih[5], xb, ai2);             \
                ah0 = dotU(RG.whh[0], xh, ah0);                                             \
                ah1 = dotU(RG.whh[1], xh, ah1);                                             \
                ah2 = dotU(RG.whh[2], xh, ah2);                                             \
                ai0 = red8dpp(ai0); ai1 = red8dpp(ai1); ai2 = red8dpp(ai2);                 \
                ah0 = red8dpp(ah0); ah1 = red8dpp(ah1); ah2 = red8dpp(ah2);                 \
                float hold = Hf[p][GI][row];                                                \
                float r  = sigmf(ai0 + ah0);                                                \
                float z  = sigmf(ai1 + ah1);                                                \
                float nn = tanhfast(ai2 + r * ah2);                                        \
                float hnew = (1.f - z) * nn + z * hold;                                     \
                float hNv = noiseu(hnew, UNF[p][(UH) + row]);                               \
                if (g == 0) {                                                               \
                    Hf[p ^ 1][GI][row] = hnew;                                              \
                    HH[p ^ 1][GI][row] = (f16)hnew;                                         \
                    HNH[row] = (f16)hNv;                                                    \
                }                                                                           \
                bar_lds();                                                                  \
                U16 xg; xg.u = *(const uint4*)&HNH[g * 8];                                  \
                float ag = red8dpp(dotU(RG.glu, xg, 0.f));                                  \
                if (g == 0) SKXH[(GOFF) + row] =                                            \
                    (f16)noiseu(hNv * sigmf(ag), UNF[p][(UG_) + row]);                      \
            }                                                                               \
            bar_lds();

#define NOISE_A2 do { if (tid >= 256) {                                                     \
                int kx = 2 * (tid >> 6);                                                    \
                UNF[p ^ 1][tid] = unifP(KK[idx + 1][kx], KK[idx + 1][kx + 1],               \
                                        (uint32_t)(bg * 64 + (tid & 63))); } } while (0)
#define NOISE_B do { int j2 = tid + 512; if (j2 < 704) {                                    \
                int kx = (j2 < 576) ? 16 : 18;                                              \
                uint32_t m2 = (j2 < 576) ? (uint32_t)(bg * 64 + (j2 & 63))                  \
                                         : (uint32_t)(bg * 128 + (j2 - 576));               \
                UNF[p ^ 1][j2] = unifP(KK[idx + 1][kx], KK[idx + 1][kx + 1], m2); } } while (0)

            GRU_STEP(rG1, SKXH + 192 + g * 16, 0, 192, 256, 0, NOISE_A2)
            GRU_STEP(rG2, (g < 4 ? SKXH + g * 16 : SKXH + 256 + (g - 4) * 16), 1, 320, 384, 64, NOISE_B)
            WSK rSK; ldSK(wh + OFF_SKIPD, row, g, rSK);
            GRU_STEP(rG3, (g < 4 ? SKXH + 64 + g * 16 : SKXH + 256 + (g - 4) * 16), 2, 448, 512, 128, ((void)0))
#undef GRU_STEP
#undef NOISE_A2
#undef NOISE_B

            float sp0, sp1;
            {
                U16 xs[5];
#pragma unroll
                for (int i = 0; i < 5; ++i) xs[i].u = *(const uint4*)&SKXH[g * 40 + 8 * i];
                float a0 = 0, a1 = 0;
#pragma unroll
                for (int i = 0; i < 5; ++i) {
                    a0 = dotU(rSK.w[i], xs[i], a0);
                    a1 = dotU(rSK.w[5 + i], xs[i], a1);
                }
                sp0 = noiseu(tanhfast(red8dpp(a0)), UNF[p][576 + row]);
                sp1 = noiseu(tanhfast(red8dpp(a1)), UNF[p][640 + row]);
                if (g == 0) { SPNH[row] = (f16)sp0; SPNH[64 + row] = (f16)sp1; }
            }
            bar_lds();

            {
                U16 xa, xb;
                xa.u = *(const uint4*)&SPNH[g * 16];
                xb.u = *(const uint4*)&SPNH[g * 16 + 8];
                float a0 = dotU(rSG.w[0], xa, 0.f); a0 = dotU(rSG.w[1], xb, a0);
                float a1 = dotU(rSG.w[2], xa, 0.f); a1 = dotU(rSG.w[3], xb, a1);
                a0 = red8dpp(a0); a1 = red8dpp(a1);
                if (g == 0) {
                    SKVH[row]      = (f16)(sp0 * sigmf(a0));
                    SKVH[64 + row] = (f16)(sp1 * sigmf(a1));
                }
            }
            bar_lds();

            {
                U16 xa, xb;
                xa.u = *(const uint4*)&SKVH[g * 16];
                xb.u = *(const uint4*)&SKVH[g * 16 + 8];
                float a = dotU(rOUT.w[0], xa, 0.f);
                a = dotU(rOUT.w[1], xb, a);
                float o = tanhfast(red8dpp(a));
                prevO = o;
                if (g == 0) outp[bg * (TT * HOPC) + t * HOPC + s * SS + row] = o;
            }
        }
        xf0 = xn0; xf1 = xn1; xf2 = xn2; xf3 = xn3;
    }
}

extern "C" void kernel_launch(void* const* d_in, const int* in_sizes, int n_in,
                              void* d_out, int out_size, void* d_ws, size_t ws_size,
                              hipStream_t stream) {
    const float* features = (const float*)d_in[0];
    const float* gfeat    = (const float*)d_in[1];
    const float* W1       = (const float*)d_in[2];
    const float* ib1      = (const float*)d_in[3];
    const float* W2       = (const float*)d_in[4];
    const float* ib2      = (const float*)d_in[5];

    float* xall = (float*)d_ws;                    // 6.55 MB
    float* fT   = xall + XALL_F32;                 // 6.55 MB
    f16*   wh   = (f16*)(fT + XALL_F32);           // 0.40 MB
    float* ug   = (float*)(wh + W_TOTAL);          // 72.1 MB (if ws permits)
    float* outp = (float*)d_out;

    const size_t need = (size_t)13508608 + UG_FLOATS * 4;
    const bool pregen = (ws_size >= need);

    SrcW sw;
    for (int i = 0; i < 14; ++i) sw.p[i] = (const float*)d_in[6 + i];

    hipLaunchKernelGGL(fargan_cvtw, dim3((W_TOTAL + 255) / 256), dim3(256), 0, stream, sw, wh);
    hipLaunchKernelGGL(fargan_tr, dim3(256), dim3(256), 0, stream, features, fT);
    hipLaunchKernelGGL(fargan_frame, dim3(TT * 8), dim3(256), 0, stream,
                       fT, gfeat, W1, ib1, W2, ib2, xall);
    if (pregen) {
        hipLaunchKernelGGL(fargan_ugen, dim3(400), dim3(256), 0, stream, ug);
        hipLaunchKernelGGL(fargan_seqpg, dim3(NBLK), dim3(NTHR), 0, stream,
                           xall, wh, ug, outp);
    } else {
        hipLaunchKernelGGL(fargan_seq, dim3(NBLK), dim3(NTHR), 0, stream, xall, wh, outp);
    }
}